// Round 10
// baseline (384.604 us; speedup 1.0000x reference)
//
#include <hip/hip_runtime.h>

#define HH 256
#define WW 256
#define CC 64
#define FF 128
#define NN 8
#define OUTC 384           // 3*C sep + C lap + F learned
#define HW (HH * WW)

typedef __attribute__((ext_vector_type(8))) short bf16x8;
typedef __attribute__((ext_vector_type(4))) float f32x4;

__device__ __forceinline__ int clampi(int v, int lo, int hi) {
    return v < lo ? lo : (v > hi ? hi : v);
}

// round-to-nearest-even fp32 -> bf16
static __device__ __forceinline__ unsigned short f2bf(float x) {
    unsigned u = __builtin_bit_cast(unsigned, x);
    u += 0x7FFFu + ((u >> 16) & 1u);
    return (unsigned short)(u >> 16);
}
static __device__ __forceinline__ unsigned packbf(float a, float b) {
    return (unsigned)f2bf(a) | ((unsigned)f2bf(b) << 16);
}
static __device__ __forceinline__ float bf2f(unsigned short s) {
    return __builtin_bit_cast(float, (unsigned)s << 16);
}
static __device__ __forceinline__ void st4(float* p, float a, float b, float c, float d) {
    f32x4 v = {a, b, c, d};
    *reinterpret_cast<f32x4*>(p) = v;      // regular cached store
}

// ---------------------------------------------------------------------------
// k0: W[f][c][3][3] fp32 -> wsW bf16 [t][kg][f][8ch]  (9*8*128*8 = 147456 B)
// ---------------------------------------------------------------------------
__global__ __launch_bounds__(256) void wT_kernel(const float* __restrict__ Wl,
                                                 unsigned short* __restrict__ wsW) {
    int e = blockIdx.x * 256 + threadIdx.x;     // (t, kg, f): 9*8*128 = 9216
    if (e >= 9216) return;
    int t = e >> 10;
    int rem = e & 1023;
    int kg = rem >> 7;
    int f = rem & 127;
    unsigned u[4];
#pragma unroll
    for (int j2 = 0; j2 < 4; ++j2) {
        float a = Wl[(size_t)f * 576 + (size_t)(kg * 8 + 2 * j2) * 9 + t];
        float b = Wl[(size_t)f * 576 + (size_t)(kg * 8 + 2 * j2 + 1) * 9 + t];
        u[j2] = packbf(a, b);
    }
    *reinterpret_cast<uint4*>(wsW + (size_t)e * 8) = make_uint4(u[0], u[1], u[2], u[3]);
}

// ---------------------------------------------------------------------------
// k1: pack x NCHW fp32 -> x-tilde NC8HW8 bf16: xt[n][cg][h][w][8ch].
// ---------------------------------------------------------------------------
__global__ __launch_bounds__(256) void pack_kernel(const float* __restrict__ x,
                                                   unsigned short* __restrict__ xt) {
    int b = blockIdx.x;                   // n*2048 + cg*256 + y
    int y = b & 255;
    int cg = (b >> 8) & 7;
    int n = b >> 11;
    int w = threadIdx.x;
    const float* xp = x + ((size_t)(n * CC + cg * 8)) * HW + (size_t)y * WW + w;
    unsigned u[4];
#pragma unroll
    for (int j2 = 0; j2 < 4; ++j2)
        u[j2] = packbf(xp[(size_t)(2 * j2) * HW], xp[(size_t)(2 * j2 + 1) * HW]);
    *reinterpret_cast<uint4*>(xt + ((size_t)((n * 8 + cg) * HH + y) * WW + w) * 8) =
        make_uint4(u[0], u[1], u[2], u[3]);
}

// ---------------------------------------------------------------------------
// k2: FUSED learned conv (bf16 MFMA, zero staging/barriers) + depthwise
// fixed filters. Identical to R9 except ALL output stores are regular
// (cached) instead of nontemporal — isolated A/B on the store path.
// ---------------------------------------------------------------------------
__global__ __launch_bounds__(256, 4) void fused_kernel(const unsigned short* __restrict__ wsW,
                                                       const unsigned short* __restrict__ xt,
                                                       const float* __restrict__ bl,
                                                       float* __restrict__ out) {
    __shared__ float lds_e[4][16][68];        // 17408 B, per-wave slabs

    int bid = blockIdx.x;
    int q = ((bid & 7) << 9) | (bid >> 3);    // bijective: 4096 = 8 * 512
    int xs = q & 1;
    int y = (q >> 1) & 255;
    int n = q >> 9;

    int tid = threadIdx.x;
    int lane = tid & 63;
    int w = tid >> 6;
    int wf = w >> 1;                          // f-half (0..1)
    int ws = w & 1;                           // px 64-segment (0..1)
    int x0 = xs * 128 + ws * 64;
    int lr = lane & 15;
    int lk = lane >> 4;

    const char* xb = reinterpret_cast<const char*>(xt) + (size_t)n * (8 * HH * WW * 16);

    int colb[4][3];
#pragma unroll
    for (int j = 0; j < 4; ++j)
#pragma unroll
        for (int dx = 0; dx < 3; ++dx)
            colb[j][dx] = clampi(x0 + j * 16 + lr + dx - 1, 0, WW - 1) * 16;

    // dw per-thread geometry: px = x0 + lane (wave covers 64 px, 256B stores)
    int pxg = x0 + lane;
    int dwyr[3], dwwc[3];
#pragma unroll
    for (int d = 0; d < 3; ++d) {
        dwyr[d] = clampi(y + d - 1, 0, HH - 1);
        dwwc[d] = clampi(pxg + d - 1, 0, WW - 1);
    }

    f32x4 acc[4][4] = {};                     // [mt (16f tile)][j (16px group)]

#pragma unroll
    for (int t = 0; t < 9; ++t) {
        int dy = t / 3, dx = t - 3 * (t / 3);
        int yc = clampi(y + dy - 1, 0, HH - 1);
#pragma unroll
        for (int kk = 0; kk < 2; ++kk) {
            int kg = kk * 4 + lk;
            size_t rowoff = ((size_t)kg * HH + yc) * (WW * 16);
            bf16x8 a4[4], b4[4];
#pragma unroll
            for (int mt = 0; mt < 4; ++mt)
                a4[mt] = *reinterpret_cast<const bf16x8*>(
                    wsW + ((size_t)(t * 8 + kg) * 128 + wf * 64 + mt * 16 + lr) * 8);
#pragma unroll
            for (int j = 0; j < 4; ++j)
                b4[j] = *reinterpret_cast<const bf16x8*>(xb + rowoff + colb[j][dx]);
#pragma unroll
            for (int mt = 0; mt < 4; ++mt)
#pragma unroll
                for (int j = 0; j < 4; ++j)
                    acc[mt][j] = __builtin_amdgcn_mfma_f32_16x16x32_bf16(
                        a4[mt], b4[j], acc[mt][j], 0, 0, 0);
        }

        // ---- dw chunk t: cg = t; 4 channels (wf*4..+3) x 64 px per wave
        if (t < 8) {
            int cg = t;
            const char* cgbase = xb + (size_t)cg * HH * (WW * 16) + wf * 8;
            uint2 c9[3][3];
#pragma unroll
            for (int r = 0; r < 3; ++r)
#pragma unroll
                for (int d = 0; d < 3; ++d)
                    c9[r][d] = *reinterpret_cast<const uint2*>(
                        cgbase + ((size_t)dwyr[r] * WW + dwwc[d]) * 16);
            size_t ob = (size_t)n * OUTC * HW + (size_t)y * WW + pxg;
#pragma unroll
            for (int i = 0; i < 4; ++i) {
                float v[3][3];
#pragma unroll
                for (int r = 0; r < 3; ++r)
#pragma unroll
                    for (int d = 0; d < 3; ++d) {
                        unsigned word = (i < 2) ? c9[r][d].x : c9[r][d].y;
                        v[r][d] = bf2f((unsigned short)((i & 1) ? (word >> 16) : (word & 0xffff)));
                    }
                int ch = cg * 8 + wf * 4 + i;
                float o0 = v[1][1];
                float o1 = (v[0][0] + 2.f * v[0][1] + v[0][2]) - (v[2][0] + 2.f * v[2][1] + v[2][2]);
                float o2 = (v[0][0] - v[0][2]) + 2.f * (v[1][0] - v[1][2]) + (v[2][0] - v[2][2]);
                float o3 = 4.f * v[1][1] - v[0][1] - v[2][1] - v[1][0] - v[1][2];
                out[ob + (size_t)(ch * 3 + 0) * HW] = o0;
                out[ob + (size_t)(ch * 3 + 1) * HW] = o1;
                out[ob + (size_t)(ch * 3 + 2) * HW] = o2;
                out[ob + (size_t)(192 + ch) * HW]   = o3;
            }
        }
    }

    // epilogue: per-wave transpose via private LDS slab; 256B regular stores
    float* le = &lds_e[w][0][0];
#pragma unroll
    for (int mt = 0; mt < 4; ++mt) {
#pragma unroll
        for (int i = 0; i < 4; ++i) {
            int f16 = lk * 4 + i;
            float bv = bl[wf * 64 + mt * 16 + f16];
#pragma unroll
            for (int j = 0; j < 4; ++j)
                le[f16 * 68 + j * 16 + lr] = acc[mt][j][i] + bv;
        }
#pragma unroll
        for (int p = 0; p < 4; ++p) {
            int f16 = p * 4 + lk;
            const float* s = &le[f16 * 68 + lr * 4];
            int f = wf * 64 + mt * 16 + f16;
            st4(out + (size_t)(n * OUTC + 256 + f) * HW + (size_t)y * WW + x0 + lr * 4,
                s[0], s[1], s[2], s[3]);
        }
    }
}

extern "C" void kernel_launch(void* const* d_in, const int* in_sizes, int n_in,
                              void* d_out, int out_size, void* d_ws, size_t ws_size,
                              hipStream_t stream) {
    const float* x  = (const float*)d_in[0];
    const float* Wl = (const float*)d_in[1];
    const float* bl = (const float*)d_in[2];
    float* out = (float*)d_out;

    unsigned short* wsW = (unsigned short*)d_ws;                            // 147456 B
    unsigned short* xt  = (unsigned short*)((char*)d_ws + 262144);          // 64 MB

    wT_kernel<<<36, 256, 0, stream>>>(Wl, wsW);
    pack_kernel<<<16384, 256, 0, stream>>>(x, xt);
    fused_kernel<<<NN * 512, 256, 0, stream>>>(wsW, xt, bl, out);
}

// Round 11
// 353.243 us; speedup vs baseline: 1.0888x; 1.0888x over previous
//
#include <hip/hip_runtime.h>

#define HH 256
#define WW 256
#define CC 64
#define FF 128
#define NN 8
#define OUTC 384           // 3*C sep + C lap + F learned
#define HW (HH * WW)

typedef __attribute__((ext_vector_type(8))) short bf16x8;
typedef __attribute__((ext_vector_type(4))) float f32x4;

__device__ __forceinline__ int clampi(int v, int lo, int hi) {
    return v < lo ? lo : (v > hi ? hi : v);
}

// round-to-nearest-even fp32 -> bf16
static __device__ __forceinline__ unsigned short f2bf(float x) {
    unsigned u = __builtin_bit_cast(unsigned, x);
    u += 0x7FFFu + ((u >> 16) & 1u);
    return (unsigned short)(u >> 16);
}
static __device__ __forceinline__ unsigned packbf(float a, float b) {
    return (unsigned)f2bf(a) | ((unsigned)f2bf(b) << 16);
}
static __device__ __forceinline__ void nts4(float* p, float a, float b, float c, float d) {
    f32x4 v = {a, b, c, d};
    __builtin_nontemporal_store(v, reinterpret_cast<f32x4*>(p));
}

// ---------------------------------------------------------------------------
// k0: W[f][c][3][3] fp32 -> wsW bf16 [t][kg][f][8ch]  (9*8*128*8 = 147456 B)
// ---------------------------------------------------------------------------
__global__ __launch_bounds__(256) void wT_kernel(const float* __restrict__ Wl,
                                                 unsigned short* __restrict__ wsW) {
    int e = blockIdx.x * 256 + threadIdx.x;     // (t, kg, f): 9*8*128 = 9216
    if (e >= 9216) return;
    int t = e >> 10;
    int rem = e & 1023;
    int kg = rem >> 7;
    int f = rem & 127;
    unsigned u[4];
#pragma unroll
    for (int j2 = 0; j2 < 4; ++j2) {
        float a = Wl[(size_t)f * 576 + (size_t)(kg * 8 + 2 * j2) * 9 + t];
        float b = Wl[(size_t)f * 576 + (size_t)(kg * 8 + 2 * j2 + 1) * 9 + t];
        u[j2] = packbf(a, b);
    }
    *reinterpret_cast<uint4*>(wsW + (size_t)e * 8) = make_uint4(u[0], u[1], u[2], u[3]);
}

// ---------------------------------------------------------------------------
// k1: pack x NCHW fp32 -> x-tilde NC8HW8 bf16: xt[n][cg][h][w][8ch].
// ---------------------------------------------------------------------------
__global__ __launch_bounds__(256) void pack_kernel(const float* __restrict__ x,
                                                   unsigned short* __restrict__ xt) {
    int b = blockIdx.x;                   // n*2048 + cg*256 + y
    int y = b & 255;
    int cg = (b >> 8) & 7;
    int n = b >> 11;
    int w = threadIdx.x;
    const float* xp = x + ((size_t)(n * CC + cg * 8)) * HW + (size_t)y * WW + w;
    unsigned u[4];
#pragma unroll
    for (int j2 = 0; j2 < 4; ++j2)
        u[j2] = packbf(xp[(size_t)(2 * j2) * HW], xp[(size_t)(2 * j2 + 1) * HW]);
    *reinterpret_cast<uint4*>(xt + ((size_t)((n * 8 + cg) * HH + y) * WW + w) * 8) =
        make_uint4(u[0], u[1], u[2], u[3]);
}

// ---------------------------------------------------------------------------
// k2: FUSED, full-row block (n, y): 512 thr / 8 waves, 256 px, 128 f.
// Learned: wave (wf, wq) = 64f x 64px, acc[4][4]; b-frags 16B direct loads
// from NC8HW8 x-tilde; no barriers in the 9-tap loop.
// dw: after tap t<8, wave w -> channel c=t*8+w, lane = 4 px, reads fp32 x
// (float4, coalesced, fp32-exact), stores 4 filter planes as 1KB nt chunks.
// Epilogue: cross-wave LDS transpose (4 mt rounds) -> 1KB nt chunks/plane.
// T1 XCD swizzle keeps the 3-row window L2-local. All out stores nt (R10).
// ---------------------------------------------------------------------------
__global__ __launch_bounds__(512, 4) void fused_kernel(const unsigned short* __restrict__ wsW,
                                                       const unsigned short* __restrict__ xt,
                                                       const float* __restrict__ x,
                                                       const float* __restrict__ bl,
                                                       float* __restrict__ out) {
    __shared__ float lds_e[32][260];          // 33280 B

    int bid = blockIdx.x;                     // 2048 = 8 XCD * 256
    int q = ((bid & 7) << 8) | (bid >> 3);    // bijective XCD-chunked swizzle
    int y = q & 255;
    int n = q >> 8;

    int tid = threadIdx.x;
    int lane = tid & 63;
    int w = tid >> 6;                         // 0..7
    int wf = w >> 2;                          // f-half (0..1)
    int wq = w & 3;                           // px quarter (0..3)
    int x0 = wq * 64;
    int lr = lane & 15;
    int lk = lane >> 4;

    const char* xb = reinterpret_cast<const char*>(xt) + (size_t)n * (8 * HH * WW * 16);

    int colx[4];
#pragma unroll
    for (int j = 0; j < 4; ++j) colx[j] = x0 + j * 16 + lr;

    // dw geometry: lane = 4 px
    int px0 = lane * 4;
    int pa = px0 >= 4 ? px0 - 4 : 0;
    int pc = px0 <= 248 ? px0 + 4 : 252;
    int yr[3];
#pragma unroll
    for (int d = 0; d < 3; ++d) yr[d] = clampi(y + d - 1, 0, HH - 1);

    f32x4 acc[4][4] = {};                     // [mt (16f tile)][j (16px group)]

#pragma unroll
    for (int t = 0; t < 9; ++t) {
        int dy = t / 3, dx = t - 3 * (t / 3);
        int yc = clampi(y + dy - 1, 0, HH - 1);
        int cb[4];
#pragma unroll
        for (int j = 0; j < 4; ++j) cb[j] = clampi(colx[j] + dx - 1, 0, WW - 1) * 16;
#pragma unroll
        for (int kk = 0; kk < 2; ++kk) {
            int kg = kk * 4 + lk;
            size_t rowoff = ((size_t)kg * HH + yc) * (WW * 16);
            bf16x8 a4[4], b4[4];
#pragma unroll
            for (int mt = 0; mt < 4; ++mt)
                a4[mt] = *reinterpret_cast<const bf16x8*>(
                    wsW + ((size_t)(t * 8 + kg) * 128 + wf * 64 + mt * 16 + lr) * 8);
#pragma unroll
            for (int j = 0; j < 4; ++j)
                b4[j] = *reinterpret_cast<const bf16x8*>(xb + rowoff + cb[j]);
#pragma unroll
            for (int mt = 0; mt < 4; ++mt)
#pragma unroll
                for (int j = 0; j < 4; ++j)
                    acc[mt][j] = __builtin_amdgcn_mfma_f32_16x16x32_bf16(
                        a4[mt], b4[j], acc[mt][j], 0, 0, 0);
        }

        // ---- dw chunk t: wave w -> channel c = t*8+w, lane = 4 px, fp32 x
        if (t < 8) {
            int c = t * 8 + w;
            const float* xc = x + ((size_t)(n * CC + c)) * HW;
            float lv[3], rv[3];
            float4 Bv[3];
#pragma unroll
            for (int r = 0; r < 3; ++r) {
                const float* rp = xc + (size_t)yr[r] * WW;
                float4 A = *(const float4*)(rp + pa);
                float4 B = *(const float4*)(rp + px0);
                float4 C = *(const float4*)(rp + pc);
                lv[r] = px0 ? A.w : B.x;
                rv[r] = (px0 < 252) ? C.x : B.w;
                Bv[r] = B;
            }
            float o0[4], o1[4], o2[4], o3[4];
#pragma unroll
            for (int j = 0; j < 4; ++j) {
                float tL = j ? (&Bv[0].x)[j - 1] : lv[0];
                float tC = (&Bv[0].x)[j];
                float tR = (j < 3) ? (&Bv[0].x)[j + 1] : rv[0];
                float mL = j ? (&Bv[1].x)[j - 1] : lv[1];
                float mC = (&Bv[1].x)[j];
                float mR = (j < 3) ? (&Bv[1].x)[j + 1] : rv[1];
                float bL = j ? (&Bv[2].x)[j - 1] : lv[2];
                float bC = (&Bv[2].x)[j];
                float bR = (j < 3) ? (&Bv[2].x)[j + 1] : rv[2];
                o0[j] = mC;
                o1[j] = (tL + 2.f * tC + tR) - (bL + 2.f * bC + bR);
                o2[j] = (tL - tR) + 2.f * (mL - mR) + (bL - bR);
                o3[j] = 4.f * mC - tC - bC - mL - mR;
            }
            float* ob = out + (size_t)n * OUTC * HW + (size_t)y * WW + px0;
            nts4(ob + (size_t)(c * 3 + 0) * HW, o0[0], o0[1], o0[2], o0[3]);
            nts4(ob + (size_t)(c * 3 + 1) * HW, o1[0], o1[1], o1[2], o1[3]);
            nts4(ob + (size_t)(c * 3 + 2) * HW, o2[0], o2[1], o2[2], o2[3]);
            nts4(ob + (size_t)(192 + c)   * HW, o3[0], o3[1], o3[2], o3[3]);
        }
    }

    // ---- epilogue: cross-wave LDS transpose, 4 rounds; 1KB nt plane chunks
#pragma unroll
    for (int mt = 0; mt < 4; ++mt) {
#pragma unroll
        for (int i = 0; i < 4; ++i) {
            int fp = wf * 16 + lk * 4 + i;
            float bv = bl[wf * 64 + mt * 16 + lk * 4 + i];
#pragma unroll
            for (int j = 0; j < 4; ++j)
                lds_e[fp][x0 + j * 16 + lr] = acc[mt][j][i] + bv;
        }
        __syncthreads();
#pragma unroll
        for (int p = 0; p < 4; ++p) {
            int fp = w * 4 + p;
            int f = (fp >> 4) * 64 + mt * 16 + (fp & 15);
            const float* s = &lds_e[fp][lane * 4];
            nts4(out + (size_t)(n * OUTC + 256 + f) * HW + (size_t)y * WW + lane * 4,
                 s[0], s[1], s[2], s[3]);
        }
        __syncthreads();
    }
}

extern "C" void kernel_launch(void* const* d_in, const int* in_sizes, int n_in,
                              void* d_out, int out_size, void* d_ws, size_t ws_size,
                              hipStream_t stream) {
    const float* x  = (const float*)d_in[0];
    const float* Wl = (const float*)d_in[1];
    const float* bl = (const float*)d_in[2];
    float* out = (float*)d_out;

    unsigned short* wsW = (unsigned short*)d_ws;                            // 147456 B
    unsigned short* xt  = (unsigned short*)((char*)d_ws + 262144);          // 64 MB

    wT_kernel<<<36, 256, 0, stream>>>(Wl, wsW);
    pack_kernel<<<16384, 256, 0, stream>>>(x, xt);
    fused_kernel<<<2048, 512, 0, stream>>>(wsW, xt, x, bl, out);
}

// Round 12
// 234.244 us; speedup vs baseline: 1.6419x; 1.5080x over previous
//
#include <hip/hip_runtime.h>

#define HH 256
#define WW 256
#define CC 64
#define FF 128
#define NN 8
#define OUTC 384           // 3*C sep + C lap + F learned
#define HW (HH * WW)

typedef __attribute__((ext_vector_type(8))) short bf16x8;
typedef __attribute__((ext_vector_type(4))) float f32x4;

__device__ __forceinline__ int clampi(int v, int lo, int hi) {
    return v < lo ? lo : (v > hi ? hi : v);
}

// round-to-nearest-even fp32 -> bf16
static __device__ __forceinline__ unsigned short f2bf(float x) {
    unsigned u = __builtin_bit_cast(unsigned, x);
    u += 0x7FFFu + ((u >> 16) & 1u);
    return (unsigned short)(u >> 16);
}
static __device__ __forceinline__ unsigned packbf(float a, float b) {
    return (unsigned)f2bf(a) | ((unsigned)f2bf(b) << 16);
}
static __device__ __forceinline__ float bf2f(unsigned short s) {
    return __builtin_bit_cast(float, (unsigned)s << 16);
}
static __device__ __forceinline__ void nts4(float* p, float a, float b, float c, float d) {
    f32x4 v = {a, b, c, d};
    __builtin_nontemporal_store(v, reinterpret_cast<f32x4*>(p));
}

// ---------------------------------------------------------------------------
// k0: W[f][c][3][3] fp32 -> wsW bf16 [t][kg][f][8ch]  (9*8*128*8 = 147456 B)
// ---------------------------------------------------------------------------
__global__ __launch_bounds__(256) void wT_kernel(const float* __restrict__ Wl,
                                                 unsigned short* __restrict__ wsW) {
    int e = blockIdx.x * 256 + threadIdx.x;     // (t, kg, f): 9*8*128 = 9216
    if (e >= 9216) return;
    int t = e >> 10;
    int rem = e & 1023;
    int kg = rem >> 7;
    int f = rem & 127;
    unsigned u[4];
#pragma unroll
    for (int j2 = 0; j2 < 4; ++j2) {
        float a = Wl[(size_t)f * 576 + (size_t)(kg * 8 + 2 * j2) * 9 + t];
        float b = Wl[(size_t)f * 576 + (size_t)(kg * 8 + 2 * j2 + 1) * 9 + t];
        u[j2] = packbf(a, b);
    }
    *reinterpret_cast<uint4*>(wsW + (size_t)e * 8) = make_uint4(u[0], u[1], u[2], u[3]);
}

// ---------------------------------------------------------------------------
// k1: pack x NCHW fp32 -> x-tilde NC8HW8 bf16: xt[n][cg][h][w][8ch].
// ---------------------------------------------------------------------------
__global__ __launch_bounds__(256) void pack_kernel(const float* __restrict__ x,
                                                   unsigned short* __restrict__ xt) {
    int b = blockIdx.x;                   // n*2048 + cg*256 + y
    int y = b & 255;
    int cg = (b >> 8) & 7;
    int n = b >> 11;
    int w = threadIdx.x;
    const float* xp = x + ((size_t)(n * CC + cg * 8)) * HW + (size_t)y * WW + w;
    unsigned u[4];
#pragma unroll
    for (int j2 = 0; j2 < 4; ++j2)
        u[j2] = packbf(xp[(size_t)(2 * j2) * HW], xp[(size_t)(2 * j2 + 1) * HW]);
    *reinterpret_cast<uint4*>(xt + ((size_t)((n * 8 + cg) * HH + y) * WW + w) * 8) =
        make_uint4(u[0], u[1], u[2], u[3]);
}

// ---------------------------------------------------------------------------
// k2: MIXED block-specialized kernel, 20480 blocks x 256 thr, interleave 1:4.
//  b%5==0 -> learned block (R8 body): 128px x 128f MFMA, no staging/barriers.
//  b%5>=1 -> dw block (R8 body): (n,cg,y), 8ch x 256px, 4 fixed filters.
// dw waves keep VMEM/HBM-write busy while learned waves stall on L2 loads.
// Per-XCD dense counters (xcd = bid&7; 5^-1 = 5 mod 8) keep image n = xcd
// and y sequential on each XCD -> xt windows stay L2-hot for both paths.
// All out stores nontemporal (R10: regular stores -50% via cache pollution).
// ---------------------------------------------------------------------------
__global__ __launch_bounds__(256, 4) void mixed_kernel(const unsigned short* __restrict__ wsW,
                                                       const unsigned short* __restrict__ xt,
                                                       const float* __restrict__ bl,
                                                       float* __restrict__ out) {
    __shared__ float lds_e[4][16][68];        // 17408 B, per-wave slabs (learned)

    int b = blockIdx.x;
    int g = b / 5;
    int r = b - g * 5;
    int xcd = b & 7;
    int cnt = g >> 3;                         // dense 0..511 per (r, xcd)

    if (r == 0) {
        // ================= learned block =================
        int n = xcd;
        int y = cnt >> 1;
        int xs = cnt & 1;

        int tid = threadIdx.x;
        int lane = tid & 63;
        int w = tid >> 6;
        int wf = w >> 1;                      // f-half (0..1)
        int ws = w & 1;                       // px 64-segment (0..1)
        int x0 = xs * 128 + ws * 64;
        int lr = lane & 15;
        int lk = lane >> 4;

        const char* xb = reinterpret_cast<const char*>(xt) + (size_t)n * (8 * HH * WW * 16);

        int colb[4][3];
#pragma unroll
        for (int j = 0; j < 4; ++j)
#pragma unroll
            for (int dx = 0; dx < 3; ++dx)
                colb[j][dx] = clampi(x0 + j * 16 + lr + dx - 1, 0, WW - 1) * 16;

        f32x4 acc[4][4] = {};                 // [mt (16f tile)][j (16px group)]

#pragma unroll
        for (int t = 0; t < 9; ++t) {
            int dy = t / 3, dx = t - 3 * (t / 3);
            int yc = clampi(y + dy - 1, 0, HH - 1);
#pragma unroll
            for (int kk = 0; kk < 2; ++kk) {
                int kg = kk * 4 + lk;
                size_t rowoff = ((size_t)kg * HH + yc) * (WW * 16);
                bf16x8 a4[4], b4[4];
#pragma unroll
                for (int mt = 0; mt < 4; ++mt)
                    a4[mt] = *reinterpret_cast<const bf16x8*>(
                        wsW + ((size_t)(t * 8 + kg) * 128 + wf * 64 + mt * 16 + lr) * 8);
#pragma unroll
                for (int j = 0; j < 4; ++j)
                    b4[j] = *reinterpret_cast<const bf16x8*>(xb + rowoff + colb[j][dx]);
#pragma unroll
                for (int mt = 0; mt < 4; ++mt)
#pragma unroll
                    for (int j = 0; j < 4; ++j)
                        acc[mt][j] = __builtin_amdgcn_mfma_f32_16x16x32_bf16(
                            a4[mt], b4[j], acc[mt][j], 0, 0, 0);
            }
        }

        // epilogue: per-wave transpose via private LDS slab; 256B nt stores
        float* le = &lds_e[w][0][0];
#pragma unroll
        for (int mt = 0; mt < 4; ++mt) {
#pragma unroll
            for (int i = 0; i < 4; ++i) {
                int f16 = lk * 4 + i;
                float bv = bl[wf * 64 + mt * 16 + f16];
#pragma unroll
                for (int j = 0; j < 4; ++j)
                    le[f16 * 68 + j * 16 + lr] = acc[mt][j][i] + bv;
            }
#pragma unroll
            for (int p = 0; p < 4; ++p) {
                int f16 = p * 4 + lk;
                const float* s = &le[f16 * 68 + lr * 4];
                int f = wf * 64 + mt * 16 + f16;
                nts4(out + (size_t)(n * OUTC + 256 + f) * HW + (size_t)y * WW + x0 + lr * 4,
                     s[0], s[1], s[2], s[3]);
            }
        }
        return;
    }

    // ================= dw block =================
    {
        int m = (r - 1) * 512 + cnt;          // dense 0..2047 per xcd
        int n = xcd;
        int cg = m >> 8;
        int y = m & 255;
        int w = threadIdx.x;

        const unsigned short* xg = xt + (size_t)(n * 8 + cg) * HH * WW * 8;
        int yr[3], wc[3];
#pragma unroll
        for (int d = 0; d < 3; ++d) {
            yr[d] = clampi(y + d - 1, 0, HH - 1);
            wc[d] = clampi(w + d - 1, 0, WW - 1);
        }
        uint4 chunk[3][3];
#pragma unroll
        for (int rr = 0; rr < 3; ++rr)
#pragma unroll
            for (int c = 0; c < 3; ++c)
                chunk[rr][c] = *reinterpret_cast<const uint4*>(
                    xg + ((size_t)yr[rr] * WW + wc[c]) * 8);

        size_t ob = (size_t)n * OUTC * HW + (size_t)y * WW + w;
#pragma unroll
        for (int j = 0; j < 8; ++j) {
            float v[3][3];
#pragma unroll
            for (int rr = 0; rr < 3; ++rr)
#pragma unroll
                for (int c = 0; c < 3; ++c) {
                    unsigned word = (&chunk[rr][c].x)[j >> 1];
                    v[rr][c] = bf2f((unsigned short)(j & 1 ? word >> 16 : word & 0xffff));
                }
            int ch = cg * 8 + j;
            float tL = v[0][0], tC = v[0][1], tR = v[0][2];
            float mL = v[1][0], mC = v[1][1], mR = v[1][2];
            float bL = v[2][0], bC = v[2][1], bR = v[2][2];
            float o0 = mC;
            float o1 = (tL + 2.f * tC + tR) - (bL + 2.f * bC + bR);
            float o2 = (tL - tR) + 2.f * (mL - mR) + (bL - bR);
            float o3 = 4.f * mC - tC - bC - mL - mR;
            __builtin_nontemporal_store(o0, out + ob + (size_t)(ch * 3 + 0) * HW);
            __builtin_nontemporal_store(o1, out + ob + (size_t)(ch * 3 + 1) * HW);
            __builtin_nontemporal_store(o2, out + ob + (size_t)(ch * 3 + 2) * HW);
            __builtin_nontemporal_store(o3, out + ob + (size_t)(192 + ch) * HW);
        }
    }
}

extern "C" void kernel_launch(void* const* d_in, const int* in_sizes, int n_in,
                              void* d_out, int out_size, void* d_ws, size_t ws_size,
                              hipStream_t stream) {
    const float* x  = (const float*)d_in[0];
    const float* Wl = (const float*)d_in[1];
    const float* bl = (const float*)d_in[2];
    float* out = (float*)d_out;

    unsigned short* wsW = (unsigned short*)d_ws;                            // 147456 B
    unsigned short* xt  = (unsigned short*)((char*)d_ws + 262144);          // 64 MB

    wT_kernel<<<36, 256, 0, stream>>>(Wl, wsW);
    pack_kernel<<<16384, 256, 0, stream>>>(x, xt);
    mixed_kernel<<<20480, 256, 0, stream>>>(wsW, xt, bl, out);
}